// Round 1
// baseline (380.225 us; speedup 1.0000x reference)
//
#include <hip/hip_runtime.h>
#include <hip/hip_bf16.h>
#include <stdint.h>

// dMoA forward: router -> dropless dispatch -> grouped map GEMM (H->F) ->
// grouped reduce GEMM (F->H) with expert-weight fold + atomic combine.
// T=8192 tokens, H=F=1024, E=8, top-k=2.

#define T_TOK 8192
#define HD 1024
#define FD 1024
#define EN 8
#define TKN 16384   // T_TOK * 2

typedef __attribute__((ext_vector_type(8))) short bf16x8;
typedef __attribute__((ext_vector_type(4))) float f32x4;

// ---------------------------------------------------------------- router
__global__ __launch_bounds__(256) void router_kernel(
    const float* __restrict__ x, const float* __restrict__ wr,
    int* __restrict__ top_e, float* __restrict__ top_w,
    int* __restrict__ counts, float* __restrict__ probsum)
{
    __shared__ float lw[EN][HD];     // transposed: lw[e][h], conflict-free reads
    __shared__ int   cnt_s[EN];
    __shared__ float ps_s[EN];
    int tid = threadIdx.x;
    for (int i = tid; i < HD * EN; i += 256) lw[i & 7][i >> 3] = wr[i];
    if (tid < EN) { cnt_s[tid] = 0; ps_s[tid] = 0.f; }
    __syncthreads();

    int wid = tid >> 6, lane = tid & 63;
    int t = blockIdx.x * 4 + wid;            // grid 2048 * 4 waves = 8192 tokens
    float acc[EN];
#pragma unroll
    for (int e = 0; e < EN; e++) acc[e] = 0.f;
    const float* xr = x + (size_t)t * HD;
    for (int i = 0; i < HD; i += 64) {
        float xv = xr[i + lane];
#pragma unroll
        for (int e = 0; e < EN; e++) acc[e] += xv * lw[e][i + lane];
    }
#pragma unroll
    for (int off = 32; off >= 1; off >>= 1) {
#pragma unroll
        for (int e = 0; e < EN; e++) acc[e] += __shfl_xor(acc[e], off, 64);
    }
    if (lane == 0) {
        float m = acc[0];
#pragma unroll
        for (int e = 1; e < EN; e++) m = fmaxf(m, acc[e]);
        float p[EN], s = 0.f;
#pragma unroll
        for (int e = 0; e < EN; e++) { p[e] = expf(acc[e] - m); s += p[e]; }
        float inv = 1.f / s;
#pragma unroll
        for (int e = 0; e < EN; e++) p[e] *= inv;
        // top-2, jax.lax.top_k tie-break: strict >, first index wins
        int e0 = 0;
#pragma unroll
        for (int e = 1; e < EN; e++) if (p[e] > p[e0]) e0 = e;
        int e1 = (e0 == 0) ? 1 : 0;
#pragma unroll
        for (int e = 0; e < EN; e++) {
            if (e == e0) continue;
            if (p[e] > p[e1]) e1 = e;
        }
        top_e[t * 2] = e0;  top_e[t * 2 + 1] = e1;
        top_w[t * 2] = p[e0]; top_w[t * 2 + 1] = p[e1];
        atomicAdd(&cnt_s[e0], 1); atomicAdd(&cnt_s[e1], 1);
#pragma unroll
        for (int e = 0; e < EN; e++) atomicAdd(&ps_s[e], p[e]);
    }
    __syncthreads();
    if (tid < EN) {
        atomicAdd(&counts[tid], cnt_s[tid]);
        atomicAdd(&probsum[tid], ps_s[tid]);
    }
}

// ------------------------------------------------------------- prep (1 thread)
__global__ void prep_kernel(const int* __restrict__ counts,
                            const float* __restrict__ probsum,
                            int* __restrict__ offs, float* __restrict__ loss_out)
{
    int off = 0; float loss = 0.f;
    for (int e = 0; e < EN; e++) {
        offs[e] = off;
        off += counts[e];
        loss += ((float)counts[e] / 16384.f) * (probsum[e] / 8192.f);
    }
    offs[EN] = off;
    *loss_out = 8.f * loss;
}

// ---------------------------------------------------------------- dispatch
__global__ __launch_bounds__(256) void dispatch_kernel(
    const int* __restrict__ top_e, const float* __restrict__ top_w,
    const int* __restrict__ offs, int* __restrict__ cursor,
    int* __restrict__ tok_list, float* __restrict__ w_list)
{
    int t = blockIdx.x * 256 + threadIdx.x;   // grid 32*256 == 8192 exactly
#pragma unroll
    for (int k = 0; k < 2; k++) {
        int e = top_e[t * 2 + k];
        int pos = atomicAdd(&cursor[e], 1);
        int i = offs[e] + pos;
        tok_list[i] = t;
        w_list[i] = top_w[t * 2 + k];
    }
}

// ------------------------------------------------------- f32 -> bf16 convert
__global__ __launch_bounds__(256) void convert_kernel(
    const float* __restrict__ in, ushort* __restrict__ outp, int n8)
{
    int i = blockIdx.x * 256 + threadIdx.x;
    if (i >= n8) return;
    const float4* p = (const float4*)in;
    float4 a = p[(size_t)i * 2], b = p[(size_t)i * 2 + 1];
    float vals[8] = {a.x, a.y, a.z, a.w, b.x, b.y, b.z, b.w};
    ushort us[8];
#pragma unroll
    for (int j = 0; j < 8; j++) {
        __hip_bfloat16 h = __float2bfloat16(vals[j]);
        us[j] = *(ushort*)&h;
    }
    *(uint4*)(outp + (size_t)i * 8) = *(uint4*)us;
}

// --------------------------------------- per-expert transpose + bf16 convert
// in: [E][A=1024][B=1024] f32, out: [E][B][A] bf16
__global__ __launch_bounds__(256) void transpose_conv_kernel(
    const float* __restrict__ in, ushort* __restrict__ outp)
{
    __shared__ float tile[32][33];
    int bid = blockIdx.x;
    int e  = bid >> 10;
    int t2 = bid & 1023;
    int tb = t2 >> 5;   // col-tile of in
    int ta = t2 & 31;   // row-tile of in
    const float* pin = in + ((size_t)e << 20);
    ushort* pout = outp + ((size_t)e << 20);
    int tx = threadIdx.x & 31, ty = threadIdx.x >> 5;  // ty 0..7
#pragma unroll
    for (int j = 0; j < 4; j++)
        tile[ty + j * 8][tx] = pin[(size_t)(ta * 32 + ty + j * 8) * 1024 + tb * 32 + tx];
    __syncthreads();
#pragma unroll
    for (int j = 0; j < 4; j++) {
        __hip_bfloat16 h = __float2bfloat16(tile[tx][ty + j * 8]);
        pout[(size_t)(tb * 32 + ty + j * 8) * 1024 + ta * 32 + tx] = *(ushort*)&h;
    }
}

// --------------------------------------------------------- grouped map GEMM
// h[row][f] = ( x[tok[row]][:] @ w1[e][:][f] ) * weight[row], stored bf16.
// xb: [T][H] bf16; w1b: [E][F][H] bf16 (B^T layout); hbuf: [TKN][F] bf16.
__global__ __launch_bounds__(256) void map_gemm(
    const ushort* __restrict__ xb, const ushort* __restrict__ w1b,
    ushort* __restrict__ hbuf,
    const int* __restrict__ tok_list, const float* __restrict__ w_list,
    const int* __restrict__ offs)
{
    __shared__ short lA[128 * 32];
    __shared__ short lB[128 * 32];
    __shared__ int   tok_s[128];
    __shared__ float wt_s[128];

    int e = blockIdx.x >> 6;
    int rb = blockIdx.x & 63;
    int base = offs[e], cnt = offs[e + 1] - base;
    int row0 = rb << 7;
    if (row0 >= cnt) return;
    int rem = cnt - row0;
    int tid = threadIdx.x;
    if (tid < 128) {
        int r = row0 + tid; if (r > cnt - 1) r = cnt - 1;   // clamp
        tok_s[tid] = tok_list[base + r];
        wt_s[tid]  = w_list[base + r];
    }
    __syncthreads();

    int lane = tid & 63, wid = tid >> 6;
    int wr = wid >> 1, wc = wid & 1;
    int nb = blockIdx.y;

    int sr = tid >> 2;             // staging row 0..63 (and +64)
    int sk = (tid & 3) << 3;       // k-segment 0/8/16/24
    const ushort* gA0 = xb + (size_t)tok_s[sr] * HD + sk;
    const ushort* gA1 = xb + (size_t)tok_s[64 + sr] * HD + sk;
    const ushort* wbase = w1b + ((size_t)e << 20);
    const ushort* gB0 = wbase + (size_t)(nb * 128 + sr) * HD + sk;
    const ushort* gB1 = wbase + (size_t)(nb * 128 + 64 + sr) * HD + sk;
    int wO0 = sr * 32 + sk;
    int wO1 = (64 + sr) * 32 + sk;

    f32x4 acc[4][4];
#pragma unroll
    for (int m = 0; m < 4; m++)
#pragma unroll
        for (int n = 0; n < 4; n++) acc[m][n] = (f32x4){0.f, 0.f, 0.f, 0.f};

    for (int k0 = 0; k0 < HD; k0 += 32) {
        uint4 a0 = *(const uint4*)(gA0 + k0);
        uint4 a1 = *(const uint4*)(gA1 + k0);
        uint4 b0 = *(const uint4*)(gB0 + k0);
        uint4 b1 = *(const uint4*)(gB1 + k0);
        __syncthreads();
        *(uint4*)&lA[wO0] = a0;
        *(uint4*)&lA[wO1] = a1;
        *(uint4*)&lB[wO0] = b0;
        *(uint4*)&lB[wO1] = b1;
        __syncthreads();
        bf16x8 af[4], bg[4];
#pragma unroll
        for (int m = 0; m < 4; m++)
            af[m] = *(const bf16x8*)&lA[(wr * 64 + m * 16 + (lane & 15)) * 32 + ((lane >> 4) << 3)];
#pragma unroll
        for (int n = 0; n < 4; n++)
            bg[n] = *(const bf16x8*)&lB[(wc * 64 + n * 16 + (lane & 15)) * 32 + ((lane >> 4) << 3)];
#pragma unroll
        for (int m = 0; m < 4; m++)
#pragma unroll
            for (int n = 0; n < 4; n++)
                acc[m][n] = __builtin_amdgcn_mfma_f32_16x16x32_bf16(af[m], bg[n], acc[m][n], 0, 0, 0);
    }

#pragma unroll
    for (int m = 0; m < 4; m++) {
        int r0 = wr * 64 + m * 16 + ((lane >> 4) << 2);
#pragma unroll
        for (int n = 0; n < 4; n++) {
            int gc = (nb << 7) + wc * 64 + n * 16 + (lane & 15);
#pragma unroll
            for (int r = 0; r < 4; r++) {
                int rl = r0 + r;
                if (rl < rem) {
                    float v = acc[m][n][r] * wt_s[rl];
                    __hip_bfloat16 hv = __float2bfloat16(v);
                    hbuf[(size_t)(base + row0 + rl) * FD + gc] = *(ushort*)&hv;
                }
            }
        }
    }
}

// ------------------------------------------------------ grouped reduce GEMM
// out[tok[row]][:] += h[row][:] @ w2[e][:][:]   (weight already folded into h)
// hbuf: [TKN][F] bf16; w2b: [E][H][F] bf16 (B^T layout); out: [T][H] f32.
__global__ __launch_bounds__(256) void reduce_gemm(
    const ushort* __restrict__ hbuf, const ushort* __restrict__ w2b,
    float* __restrict__ out,
    const int* __restrict__ tok_list, const int* __restrict__ offs)
{
    __shared__ short lA[128 * 32];
    __shared__ short lB[128 * 32];
    __shared__ int   tok_s[128];

    int e = blockIdx.x >> 6;
    int rb = blockIdx.x & 63;
    int base = offs[e], cnt = offs[e + 1] - base;
    int row0 = rb << 7;
    if (row0 >= cnt) return;
    int rem = cnt - row0;
    int tid = threadIdx.x;
    if (tid < 128) {
        int r = row0 + tid; if (r > cnt - 1) r = cnt - 1;
        tok_s[tid] = tok_list[base + r];
    }
    __syncthreads();

    int lane = tid & 63, wid = tid >> 6;
    int wr = wid >> 1, wc = wid & 1;
    int nb = blockIdx.y;

    int sr = tid >> 2;
    int sk = (tid & 3) << 3;
    int ra0 = row0 + sr;        if (ra0 > cnt - 1) ra0 = cnt - 1;
    int ra1 = row0 + 64 + sr;   if (ra1 > cnt - 1) ra1 = cnt - 1;
    const ushort* gA0 = hbuf + (size_t)(base + ra0) * FD + sk;
    const ushort* gA1 = hbuf + (size_t)(base + ra1) * FD + sk;
    const ushort* wbase = w2b + ((size_t)e << 20);
    const ushort* gB0 = wbase + (size_t)(nb * 128 + sr) * FD + sk;
    const ushort* gB1 = wbase + (size_t)(nb * 128 + 64 + sr) * FD + sk;
    int wO0 = sr * 32 + sk;
    int wO1 = (64 + sr) * 32 + sk;

    f32x4 acc[4][4];
#pragma unroll
    for (int m = 0; m < 4; m++)
#pragma unroll
        for (int n = 0; n < 4; n++) acc[m][n] = (f32x4){0.f, 0.f, 0.f, 0.f};

    for (int k0 = 0; k0 < FD; k0 += 32) {
        uint4 a0 = *(const uint4*)(gA0 + k0);
        uint4 a1 = *(const uint4*)(gA1 + k0);
        uint4 b0 = *(const uint4*)(gB0 + k0);
        uint4 b1 = *(const uint4*)(gB1 + k0);
        __syncthreads();
        *(uint4*)&lA[wO0] = a0;
        *(uint4*)&lA[wO1] = a1;
        *(uint4*)&lB[wO0] = b0;
        *(uint4*)&lB[wO1] = b1;
        __syncthreads();
        bf16x8 af[4], bg[4];
#pragma unroll
        for (int m = 0; m < 4; m++)
            af[m] = *(const bf16x8*)&lA[(wr * 64 + m * 16 + (lane & 15)) * 32 + ((lane >> 4) << 3)];
#pragma unroll
        for (int n = 0; n < 4; n++)
            bg[n] = *(const bf16x8*)&lB[(wc * 64 + n * 16 + (lane & 15)) * 32 + ((lane >> 4) << 3)];
#pragma unroll
        for (int m = 0; m < 4; m++)
#pragma unroll
            for (int n = 0; n < 4; n++)
                acc[m][n] = __builtin_amdgcn_mfma_f32_16x16x32_bf16(af[m], bg[n], acc[m][n], 0, 0, 0);
    }

#pragma unroll
    for (int m = 0; m < 4; m++) {
        int r0 = wr * 64 + m * 16 + ((lane >> 4) << 2);
#pragma unroll
        for (int n = 0; n < 4; n++) {
            int gc = (nb << 7) + wc * 64 + n * 16 + (lane & 15);
#pragma unroll
            for (int r = 0; r < 4; r++) {
                int rl = r0 + r;
                if (rl < rem)
                    atomicAdd(&out[(size_t)tok_s[rl] * HD + gc], acc[m][n][r]);
            }
        }
    }
}

// ---------------------------------------------------------------- launcher
extern "C" void kernel_launch(void* const* d_in, const int* in_sizes, int n_in,
                              void* d_out, int out_size, void* d_ws, size_t ws_size,
                              hipStream_t stream)
{
    const float* x   = (const float*)d_in[0];
    const float* wrt = (const float*)d_in[1];
    const float* w1  = (const float*)d_in[2];
    const float* w2  = (const float*)d_in[3];
    float* out = (float*)d_out;

    // workspace carve (~80.3 MB)
    uint8_t* ws = (uint8_t*)d_ws;
    ushort* xb   = (ushort*)(ws);                    // 16 MB  [T][H] bf16
    ushort* w1b  = (ushort*)(ws + (16u << 20));      // 16 MB  [E][F][H] bf16
    ushort* w2b  = (ushort*)(ws + (32u << 20));      // 16 MB  [E][H][F] bf16
    ushort* hbuf = (ushort*)(ws + (48u << 20));      // 32 MB  [TKN][F] bf16
    uint8_t* p80 = ws + (80u << 20);
    int*   tok_list = (int*)(p80);                   // 64 KB
    float* w_list   = (float*)(p80 + (64u << 10));   // 64 KB
    int*   top_e    = (int*)(p80 + (128u << 10));    // 64 KB
    float* top_w    = (float*)(p80 + (192u << 10));  // 64 KB
    uint8_t* ctr    = p80 + (256u << 10);
    int*   counts   = (int*)(ctr);
    float* probsum  = (float*)(ctr + 64);
    int*   cursor   = (int*)(ctr + 128);
    int*   offs     = (int*)(ctr + 192);
    float* loss_out = out + 8388608;

    hipMemsetAsync(d_out, 0, (size_t)out_size * sizeof(float), stream);
    hipMemsetAsync(ctr, 0, 256, stream);

    router_kernel<<<2048, 256, 0, stream>>>(x, wrt, top_e, top_w, counts, probsum);
    prep_kernel<<<1, 1, 0, stream>>>(counts, probsum, offs, loss_out);
    dispatch_kernel<<<32, 256, 0, stream>>>(top_e, top_w, offs, cursor, tok_list, w_list);
    convert_kernel<<<4096, 256, 0, stream>>>(x, xb, 1048576);
    transpose_conv_kernel<<<8192, 256, 0, stream>>>(w1, w1b);
    transpose_conv_kernel<<<8192, 256, 0, stream>>>(w2, w2b);
    map_gemm<<<dim3(512, 8), 256, 0, stream>>>(xb, w1b, hbuf, tok_list, w_list, offs);
    reduce_gemm<<<dim3(512, 8), 256, 0, stream>>>(hbuf, w2b, out, tok_list, offs);
}

// Round 2
// 329.372 us; speedup vs baseline: 1.1544x; 1.1544x over previous
//
#include <hip/hip_runtime.h>
#include <hip/hip_bf16.h>
#include <stdint.h>

// dMoA forward: router(+x->bf16) -> dispatch -> grouped map GEMM (H->F) ->
// grouped reduce GEMM (F->H, per-(t,k) rows) -> coalesced combine.
// T=8192 tokens, H=F=1024, E=8, top-k=2.

#define HD 1024
#define FD 1024
#define EN 8

typedef __attribute__((ext_vector_type(8))) short bf16x8;
typedef __attribute__((ext_vector_type(4))) float f32x4;

__device__ __forceinline__ void gload16(const void* g, void* l) {
    __builtin_amdgcn_global_load_lds(
        (const __attribute__((address_space(1))) unsigned int*)g,
        (__attribute__((address_space(3))) unsigned int*)l, 16, 0, 0);
}

__device__ __forceinline__ ushort f2bf(float v) {
    __hip_bfloat16 h = __float2bfloat16(v);
    return *(ushort*)&h;
}
__device__ __forceinline__ float bf2f(ushort u) {
    unsigned int w = ((unsigned int)u) << 16;
    float f; __builtin_memcpy(&f, &w, 4); return f;
}

// ------------------------------------------------- router (+ x -> bf16 cast)
__global__ __launch_bounds__(256) void router_kernel(
    const float* __restrict__ x, const float* __restrict__ wrt,
    ushort* __restrict__ xb,
    int* __restrict__ top_e, float* __restrict__ top_w,
    int* __restrict__ counts, float* __restrict__ probsum)
{
    __shared__ int   cnt_s[EN];
    __shared__ float ps_s[EN];
    int tid = threadIdx.x;
    if (tid < EN) { cnt_s[tid] = 0; ps_s[tid] = 0.f; }
    __syncthreads();

    int wid = tid >> 6, lane = tid & 63;
    int t = blockIdx.x * 4 + wid;            // grid 2048 * 4 waves = 8192
    const float4* xr4 = (const float4*)(x + (size_t)t * HD);
    ushort4* xbo = (ushort4*)(xb + (size_t)t * HD);
    float acc[EN];
#pragma unroll
    for (int e = 0; e < EN; e++) acc[e] = 0.f;
#pragma unroll
    for (int it = 0; it < 4; it++) {
        float4 xv = xr4[it * 64 + lane];
        ushort4 o; o.x = f2bf(xv.x); o.y = f2bf(xv.y); o.z = f2bf(xv.z); o.w = f2bf(xv.w);
        xbo[it * 64 + lane] = o;
        int h0 = it * 256 + lane * 4;
        float xs[4] = {xv.x, xv.y, xv.z, xv.w};
#pragma unroll
        for (int j = 0; j < 4; j++) {
            const float4* wp = (const float4*)(wrt + (size_t)(h0 + j) * EN);
            float4 wa = wp[0], wb = wp[1];
            acc[0] += xs[j] * wa.x; acc[1] += xs[j] * wa.y;
            acc[2] += xs[j] * wa.z; acc[3] += xs[j] * wa.w;
            acc[4] += xs[j] * wb.x; acc[5] += xs[j] * wb.y;
            acc[6] += xs[j] * wb.z; acc[7] += xs[j] * wb.w;
        }
    }
#pragma unroll
    for (int off = 32; off >= 1; off >>= 1) {
#pragma unroll
        for (int e = 0; e < EN; e++) acc[e] += __shfl_xor(acc[e], off, 64);
    }
    if (lane == 0) {
        float m = acc[0];
#pragma unroll
        for (int e = 1; e < EN; e++) m = fmaxf(m, acc[e]);
        float p[EN], s = 0.f;
#pragma unroll
        for (int e = 0; e < EN; e++) { p[e] = expf(acc[e] - m); s += p[e]; }
        float inv = 1.f / s;
#pragma unroll
        for (int e = 0; e < EN; e++) p[e] *= inv;
        int e0 = 0;
#pragma unroll
        for (int e = 1; e < EN; e++) if (p[e] > p[e0]) e0 = e;   // strict >, first wins
        int e1 = (e0 == 0) ? 1 : 0;
#pragma unroll
        for (int e = 0; e < EN; e++) {
            if (e == e0) continue;
            if (p[e] > p[e1]) e1 = e;
        }
        top_e[t * 2] = e0;  top_e[t * 2 + 1] = e1;
        top_w[t * 2] = p[e0]; top_w[t * 2 + 1] = p[e1];
        atomicAdd(&cnt_s[e0], 1); atomicAdd(&cnt_s[e1], 1);
#pragma unroll
        for (int e = 0; e < EN; e++) atomicAdd(&ps_s[e], p[e]);
    }
    __syncthreads();
    if (tid < EN) {
        atomicAdd(&counts[tid], cnt_s[tid]);
        atomicAdd(&probsum[tid], ps_s[tid]);
    }
}

// ------------------------------------------------------------- prep (1 thread)
__global__ void prep_kernel(const int* __restrict__ counts,
                            const float* __restrict__ probsum,
                            int* __restrict__ offs, float* __restrict__ loss_out)
{
    int off = 0; float loss = 0.f;
    for (int e = 0; e < EN; e++) {
        offs[e] = off;
        off += counts[e];
        loss += ((float)counts[e] / 16384.f) * (probsum[e] / 8192.f);
    }
    offs[EN] = off;
    *loss_out = 8.f * loss;
}

// ---------------------------------------------------------------- dispatch
__global__ __launch_bounds__(256) void dispatch_kernel(
    const int* __restrict__ top_e, const float* __restrict__ top_w,
    const int* __restrict__ offs, int* __restrict__ cursor,
    int* __restrict__ tok_list, float* __restrict__ w_list)
{
    int t = blockIdx.x * 256 + threadIdx.x;   // grid 32*256 == 8192 exactly
#pragma unroll
    for (int k = 0; k < 2; k++) {
        int e = top_e[t * 2 + k];
        int pos = atomicAdd(&cursor[e], 1);
        int i = offs[e] + pos;
        tok_list[i] = t * 2 + k;              // encode (token, k)
        w_list[i] = top_w[t * 2 + k];
    }
}

// --------------------------------------- per-expert transpose + bf16 convert
// w1: [E][1024][1024] f32 -> w1b [E][1024][1024] bf16 transposed; same for w2.
__global__ __launch_bounds__(256) void transpose_conv_kernel(
    const float* __restrict__ w1, const float* __restrict__ w2,
    ushort* __restrict__ w1b, ushort* __restrict__ w2b)
{
    __shared__ float tile[32][33];
    int bid = blockIdx.x;
    const float* in; ushort* outp;
    if (bid >= 8192) { in = w2; outp = w2b; bid -= 8192; }
    else             { in = w1; outp = w1b; }
    int e  = bid >> 10;
    int t2 = bid & 1023;
    int tb = t2 >> 5;
    int ta = t2 & 31;
    const float* pin = in + ((size_t)e << 20);
    ushort* pout = outp + ((size_t)e << 20);
    int tx = threadIdx.x & 31, ty = threadIdx.x >> 5;  // ty 0..7
#pragma unroll
    for (int j = 0; j < 4; j++)
        tile[ty + j * 8][tx] = pin[(size_t)(ta * 32 + ty + j * 8) * 1024 + tb * 32 + tx];
    __syncthreads();
#pragma unroll
    for (int j = 0; j < 4; j++)
        pout[(size_t)(tb * 32 + ty + j * 8) * 1024 + ta * 32 + tx] =
            f2bf(tile[tx][ty + j * 8]);
}

// =================== grouped GEMM core (shared by map / reduce) =============
// 128x128 tile, BK=64, 4 waves, global_load_lds(16B), XOR-swizzled LDS.
// LDS tile: [128 rows][64 shorts] = 128B rows; phys_byte = row*128 +
// ((slot ^ (row&7))*16 + within), written linearly by gload_lds with the
// inverse swizzle applied to the per-lane GLOBAL source address (rule #21).

// --------------------------------------------------------- grouped map GEMM
__global__ __launch_bounds__(256) void map_gemm(
    const ushort* __restrict__ xb, const ushort* __restrict__ w1b,
    ushort* __restrict__ hbuf,
    const int* __restrict__ tok_list, const float* __restrict__ w_list,
    const int* __restrict__ offs)
{
    __shared__ __align__(16) short lA[128 * 64];
    __shared__ __align__(16) short lB[128 * 64];
    __shared__ int   tok_s[128];
    __shared__ float wt_s[128];

    int e = blockIdx.x >> 6;
    int rb = blockIdx.x & 63;
    int base = offs[e], cnt = offs[e + 1] - base;
    int row0 = rb << 7;
    if (row0 >= cnt) return;
    int rem = cnt - row0;
    int tid = threadIdx.x;
    if (tid < 128) {
        int r = row0 + tid; if (r > cnt - 1) r = cnt - 1;   // clamp
        tok_s[tid] = tok_list[base + r];
        wt_s[tid]  = w_list[base + r];
    }
    __syncthreads();

    int lane = tid & 63, wid = tid >> 6;
    int wr = wid >> 1, wc = wid & 1;
    int nb = blockIdx.y;

    // staging source pointers (4 A + 4 B per thread), pre-swizzled k-segment
    int srl  = lane >> 3;                         // row low bits == row&7
    int kseg = ((lane & 7) ^ srl) << 3;           // shorts within row
    const ushort* pA[4]; const ushort* pB[4];
    const ushort* wbase = w1b + ((size_t)e << 20);
#pragma unroll
    for (int i = 0; i < 4; i++) {
        int row = wid * 32 + i * 8 + srl;
        pA[i] = xb + (size_t)(tok_s[row] >> 1) * HD + kseg;
        pB[i] = wbase + (size_t)(nb * 128 + row) * HD + kseg;
    }
    short* ldsA = lA + wid * 2048;   // wave-uniform: wid*4096 bytes
    short* ldsB = lB + wid * 2048;

    f32x4 acc[4][4];
#pragma unroll
    for (int m = 0; m < 4; m++)
#pragma unroll
        for (int n = 0; n < 4; n++) acc[m][n] = (f32x4){0.f, 0.f, 0.f, 0.f};

    for (int k0 = 0; k0 < HD; k0 += 64) {
#pragma unroll
        for (int i = 0; i < 4; i++) {
            gload16(pA[i], ldsA + i * 512);
            gload16(pB[i], ldsB + i * 512);
            pA[i] += 64; pB[i] += 64;
        }
        __syncthreads();
        bf16x8 af[4][2], bg[4][2];
        int rx = lane & 7, hi = lane >> 4, lo = lane & 15;
#pragma unroll
        for (int m = 0; m < 4; m++) {
            int R = wr * 64 + m * 16 + lo;
#pragma unroll
            for (int ks = 0; ks < 2; ks++)
                af[m][ks] = *(const bf16x8*)&lA[R * 64 + (((ks * 4 + hi) ^ rx) << 3)];
        }
#pragma unroll
        for (int n = 0; n < 4; n++) {
            int R = wc * 64 + n * 16 + lo;
#pragma unroll
            for (int ks = 0; ks < 2; ks++)
                bg[n][ks] = *(const bf16x8*)&lB[R * 64 + (((ks * 4 + hi) ^ rx) << 3)];
        }
#pragma unroll
        for (int ks = 0; ks < 2; ks++)
#pragma unroll
            for (int m = 0; m < 4; m++)
#pragma unroll
                for (int n = 0; n < 4; n++)
                    acc[m][n] = __builtin_amdgcn_mfma_f32_16x16x32_bf16(af[m][ks], bg[n][ks], acc[m][n], 0, 0, 0);
        __syncthreads();
    }

    // ---- epilogue: weight-fold, bf16, LDS transpose, 16B coalesced stores
    short* ep = (wid < 2 ? lA : lB) + (wid & 1) * 4096;   // 8KB per wave
    int lo = lane & 15, hi = lane >> 4;
#pragma unroll
    for (int m = 0; m < 4; m++)
#pragma unroll
        for (int r = 0; r < 4; r++) {
            int row_l = m * 16 + hi * 4 + r;
            int rswz = (row_l & 7) << 4;
            float w = wt_s[wr * 64 + row_l];
#pragma unroll
            for (int n = 0; n < 4; n++) {
                int colb = (n * 16 + lo) * 2;
                ep[(row_l * 128 + (colb ^ rswz)) >> 1] = f2bf(acc[m][n][r] * w);
            }
        }
    __syncthreads();
    size_t outbase = (size_t)(base + row0);
    int colg0 = (nb << 7) + wc * 64;
#pragma unroll
    for (int j = 0; j < 8; j++) {
        int row_l = j * 8 + (lane >> 3);
        int r_blk = wr * 64 + row_l;
        int sb = ((lane & 7) * 16) ^ ((row_l & 7) << 4);
        bf16x8 v = *(const bf16x8*)&ep[(row_l * 128 + sb) >> 1];
        if (r_blk < rem)
            *(bf16x8*)&hbuf[(outbase + r_blk) * FD + colg0 + (lane & 7) * 8] = v;
    }
}

// ------------------------------------------------------ grouped reduce GEMM
// obuf[v][:] = h[row][:] @ w2[e]  (v = tok_list row id = t*2+k), bf16 out.
__global__ __launch_bounds__(256) void reduce_gemm(
    const ushort* __restrict__ hbuf, const ushort* __restrict__ w2b,
    ushort* __restrict__ obuf,
    const int* __restrict__ tok_list, const int* __restrict__ offs)
{
    __shared__ __align__(16) short lA[128 * 64];
    __shared__ __align__(16) short lB[128 * 64];
    __shared__ int tok_s[128];

    int e = blockIdx.x >> 6;
    int rb = blockIdx.x & 63;
    int base = offs[e], cnt = offs[e + 1] - base;
    int row0 = rb << 7;
    if (row0 >= cnt) return;
    int rem = cnt - row0;
    int tid = threadIdx.x;
    if (tid < 128) {
        int r = row0 + tid; if (r > cnt - 1) r = cnt - 1;
        tok_s[tid] = tok_list[base + r];
    }
    __syncthreads();

    int lane = tid & 63, wid = tid >> 6;
    int wr = wid >> 1, wc = wid & 1;
    int nb = blockIdx.y;

    int srl  = lane >> 3;
    int kseg = ((lane & 7) ^ srl) << 3;
    const ushort* pA[4]; const ushort* pB[4];
    const ushort* wbase = w2b + ((size_t)e << 20);
#pragma unroll
    for (int i = 0; i < 4; i++) {
        int row = wid * 32 + i * 8 + srl;
        int ar = row0 + row; if (ar > cnt - 1) ar = cnt - 1;
        pA[i] = hbuf + (size_t)(base + ar) * FD + kseg;
        pB[i] = wbase + (size_t)(nb * 128 + row) * FD + kseg;
    }
    short* ldsA = lA + wid * 2048;
    short* ldsB = lB + wid * 2048;

    f32x4 acc[4][4];
#pragma unroll
    for (int m = 0; m < 4; m++)
#pragma unroll
        for (int n = 0; n < 4; n++) acc[m][n] = (f32x4){0.f, 0.f, 0.f, 0.f};

    for (int k0 = 0; k0 < FD; k0 += 64) {
#pragma unroll
        for (int i = 0; i < 4; i++) {
            gload16(pA[i], ldsA + i * 512);
            gload16(pB[i], ldsB + i * 512);
            pA[i] += 64; pB[i] += 64;
        }
        __syncthreads();
        bf16x8 af[4][2], bg[4][2];
        int rx = lane & 7, hi = lane >> 4, lo = lane & 15;
#pragma unroll
        for (int m = 0; m < 4; m++) {
            int R = wr * 64 + m * 16 + lo;
#pragma unroll
            for (int ks = 0; ks < 2; ks++)
                af[m][ks] = *(const bf16x8*)&lA[R * 64 + (((ks * 4 + hi) ^ rx) << 3)];
        }
#pragma unroll
        for (int n = 0; n < 4; n++) {
            int R = wc * 64 + n * 16 + lo;
#pragma unroll
            for (int ks = 0; ks < 2; ks++)
                bg[n][ks] = *(const bf16x8*)&lB[R * 64 + (((ks * 4 + hi) ^ rx) << 3)];
        }
#pragma unroll
        for (int ks = 0; ks < 2; ks++)
#pragma unroll
            for (int m = 0; m < 4; m++)
#pragma unroll
                for (int n = 0; n < 4; n++)
                    acc[m][n] = __builtin_amdgcn_mfma_f32_16x16x32_bf16(af[m][ks], bg[n][ks], acc[m][n], 0, 0, 0);
        __syncthreads();
    }

    // ---- epilogue: bf16, LDS transpose, scatter rows (128B segments)
    short* ep = (wid < 2 ? lA : lB) + (wid & 1) * 4096;
    int lo = lane & 15, hi = lane >> 4;
#pragma unroll
    for (int m = 0; m < 4; m++)
#pragma unroll
        for (int r = 0; r < 4; r++) {
            int row_l = m * 16 + hi * 4 + r;
            int rswz = (row_l & 7) << 4;
#pragma unroll
            for (int n = 0; n < 4; n++) {
                int colb = (n * 16 + lo) * 2;
                ep[(row_l * 128 + (colb ^ rswz)) >> 1] = f2bf(acc[m][n][r]);
            }
        }
    __syncthreads();
    int colg0 = (nb << 7) + wc * 64;
#pragma unroll
    for (int j = 0; j < 8; j++) {
        int row_l = j * 8 + (lane >> 3);
        int r_blk = wr * 64 + row_l;
        int sb = ((lane & 7) * 16) ^ ((row_l & 7) << 4);
        bf16x8 v = *(const bf16x8*)&ep[(row_l * 128 + sb) >> 1];
        if (r_blk < rem)
            *(bf16x8*)&obuf[(size_t)tok_s[r_blk] * HD + colg0 + (lane & 7) * 8] = v;
    }
}

// ------------------------------------------------------------------ combine
// out[t][h] = obuf[2t][h] + obuf[2t+1][h]; fully coalesced.
__global__ __launch_bounds__(256) void combine_kernel(
    const ushort* __restrict__ obuf, float* __restrict__ out)
{
    int g = blockIdx.x * 256 + threadIdx.x;      // grid 4096 -> 1M threads
    int t = g >> 7, c8 = (g & 127) << 3;
    const ushort* p = obuf + (size_t)t * 2048 + c8;
    bf16x8 a = *(const bf16x8*)p;
    bf16x8 b = *(const bf16x8*)(p + 1024);
    float o[8];
#pragma unroll
    for (int i = 0; i < 8; i++)
        o[i] = bf2f((ushort)a[i]) + bf2f((ushort)b[i]);
    float* q = out + (size_t)t * HD + c8;
    *(float4*)q       = (float4){o[0], o[1], o[2], o[3]};
    *(float4*)(q + 4) = (float4){o[4], o[5], o[6], o[7]};
}

// ---------------------------------------------------------------- launcher
extern "C" void kernel_launch(void* const* d_in, const int* in_sizes, int n_in,
                              void* d_out, int out_size, void* d_ws, size_t ws_size,
                              hipStream_t stream)
{
    const float* x   = (const float*)d_in[0];
    const float* wrt = (const float*)d_in[1];
    const float* w1  = (const float*)d_in[2];
    const float* w2  = (const float*)d_in[3];
    float* out = (float*)d_out;

    // workspace carve (~80.3 MB); obuf aliases xb+w1b (dead after map_gemm)
    uint8_t* ws = (uint8_t*)d_ws;
    ushort* xb   = (ushort*)(ws);                    // 16 MB  [T][H] bf16
    ushort* w1b  = (ushort*)(ws + (16u << 20));      // 16 MB  [E][F][H] bf16
    ushort* obuf = (ushort*)(ws);                    // 32 MB  [2T][H] bf16 (alias)
    ushort* w2b  = (ushort*)(ws + (32u << 20));      // 16 MB  [E][H][F] bf16
    ushort* hbuf = (ushort*)(ws + (48u << 20));      // 32 MB  [2T][F] bf16
    uint8_t* p80 = ws + (80u << 20);
    int*   tok_list = (int*)(p80);                   // 64 KB
    float* w_list   = (float*)(p80 + (64u << 10));   // 64 KB
    int*   top_e    = (int*)(p80 + (128u << 10));    // 64 KB
    float* top_w    = (float*)(p80 + (192u << 10));  // 64 KB
    uint8_t* ctr    = p80 + (256u << 10);
    int*   counts   = (int*)(ctr);
    float* probsum  = (float*)(ctr + 64);
    int*   cursor   = (int*)(ctr + 128);
    int*   offs     = (int*)(ctr + 192);
    float* loss_out = out + 8388608;

    hipMemsetAsync(ctr, 0, 256, stream);

    router_kernel<<<2048, 256, 0, stream>>>(x, wrt, xb, top_e, top_w, counts, probsum);
    prep_kernel<<<1, 1, 0, stream>>>(counts, probsum, offs, loss_out);
    dispatch_kernel<<<32, 256, 0, stream>>>(top_e, top_w, offs, cursor, tok_list, w_list);
    transpose_conv_kernel<<<16384, 256, 0, stream>>>(w1, w2, w1b, w2b);
    map_gemm<<<dim3(512, 8), 256, 0, stream>>>(xb, w1b, hbuf, tok_list, w_list, offs);
    reduce_gemm<<<dim3(512, 8), 256, 0, stream>>>(hbuf, w2b, obuf, tok_list, offs);
    combine_kernel<<<4096, 256, 0, stream>>>(obuf, out);
}

// Round 3
// 251.444 us; speedup vs baseline: 1.5122x; 1.3099x over previous
//
#include <hip/hip_runtime.h>
#include <hip/hip_bf16.h>
#include <stdint.h>

// dMoA forward: router(+x->bf16) -> dispatch (ballot-aggregated) ->
// grouped map GEMM (H->F) -> grouped reduce GEMM (F->H, per-(t,k) rows) ->
// coalesced combine.  T=8192 tokens, H=F=1024, E=8, top-k=2.

#define HD 1024
#define FD 1024
#define EN 8

typedef __attribute__((ext_vector_type(8))) short bf16x8;
typedef __attribute__((ext_vector_type(4))) float f32x4;

__device__ __forceinline__ void gload16(const void* g, void* l) {
    __builtin_amdgcn_global_load_lds(
        (const __attribute__((address_space(1))) unsigned int*)g,
        (__attribute__((address_space(3))) unsigned int*)l, 16, 0, 0);
}

__device__ __forceinline__ ushort f2bf(float v) {
    __hip_bfloat16 h = __float2bfloat16(v);
    return *(ushort*)&h;
}
__device__ __forceinline__ float bf2f(ushort u) {
    unsigned int w = ((unsigned int)u) << 16;
    float f; __builtin_memcpy(&f, &w, 4); return f;
}

// ------------------------------------------------- router (+ x -> bf16 cast)
__global__ __launch_bounds__(256) void router_kernel(
    const float* __restrict__ x, const float* __restrict__ wrt,
    ushort* __restrict__ xb,
    int* __restrict__ top_e, float* __restrict__ top_w,
    int* __restrict__ counts, float* __restrict__ probsum)
{
    __shared__ int   cnt_s[EN];
    __shared__ float ps_s[EN];
    int tid = threadIdx.x;
    if (tid < EN) { cnt_s[tid] = 0; ps_s[tid] = 0.f; }
    __syncthreads();

    int wid = tid >> 6, lane = tid & 63;
    int t = blockIdx.x * 4 + wid;            // grid 2048 * 4 waves = 8192
    const float4* xr4 = (const float4*)(x + (size_t)t * HD);
    ushort4* xbo = (ushort4*)(xb + (size_t)t * HD);
    float acc[EN];
#pragma unroll
    for (int e = 0; e < EN; e++) acc[e] = 0.f;
#pragma unroll
    for (int it = 0; it < 4; it++) {
        float4 xv = xr4[it * 64 + lane];
        ushort4 o; o.x = f2bf(xv.x); o.y = f2bf(xv.y); o.z = f2bf(xv.z); o.w = f2bf(xv.w);
        xbo[it * 64 + lane] = o;
        int h0 = it * 256 + lane * 4;
        float xs[4] = {xv.x, xv.y, xv.z, xv.w};
#pragma unroll
        for (int j = 0; j < 4; j++) {
            const float4* wp = (const float4*)(wrt + (size_t)(h0 + j) * EN);
            float4 wa = wp[0], wb = wp[1];
            acc[0] += xs[j] * wa.x; acc[1] += xs[j] * wa.y;
            acc[2] += xs[j] * wa.z; acc[3] += xs[j] * wa.w;
            acc[4] += xs[j] * wb.x; acc[5] += xs[j] * wb.y;
            acc[6] += xs[j] * wb.z; acc[7] += xs[j] * wb.w;
        }
    }
#pragma unroll
    for (int off = 32; off >= 1; off >>= 1) {
#pragma unroll
        for (int e = 0; e < EN; e++) acc[e] += __shfl_xor(acc[e], off, 64);
    }
    if (lane == 0) {
        float m = acc[0];
#pragma unroll
        for (int e = 1; e < EN; e++) m = fmaxf(m, acc[e]);
        float p[EN], s = 0.f;
#pragma unroll
        for (int e = 0; e < EN; e++) { p[e] = expf(acc[e] - m); s += p[e]; }
        float inv = 1.f / s;
#pragma unroll
        for (int e = 0; e < EN; e++) p[e] *= inv;
        int e0 = 0;
#pragma unroll
        for (int e = 1; e < EN; e++) if (p[e] > p[e0]) e0 = e;   // strict >, first wins
        int e1 = (e0 == 0) ? 1 : 0;
#pragma unroll
        for (int e = 0; e < EN; e++) {
            if (e == e0) continue;
            if (p[e] > p[e1]) e1 = e;
        }
        top_e[t * 2] = e0;  top_e[t * 2 + 1] = e1;
        top_w[t * 2] = p[e0]; top_w[t * 2 + 1] = p[e1];
        atomicAdd(&cnt_s[e0], 1); atomicAdd(&cnt_s[e1], 1);
#pragma unroll
        for (int e = 0; e < EN; e++) atomicAdd(&ps_s[e], p[e]);
    }
    __syncthreads();
    if (tid < EN) {
        atomicAdd(&counts[tid], cnt_s[tid]);
        atomicAdd(&probsum[tid], ps_s[tid]);
    }
}

// ------------------------------------------------------------- prep (1 thread)
__global__ void prep_kernel(const int* __restrict__ counts,
                            const float* __restrict__ probsum,
                            int* __restrict__ offs, float* __restrict__ loss_out)
{
    int off = 0; float loss = 0.f;
    for (int e = 0; e < EN; e++) {
        offs[e] = off;
        off += counts[e];
        loss += ((float)counts[e] / 16384.f) * (probsum[e] / 8192.f);
    }
    offs[EN] = off;
    *loss_out = 8.f * loss;
}

// ---------------------------------------------------------------- dispatch
// Per-wave ballot aggregation: 1 atomic per (wave, expert, k) onto padded
// cachelines -> ~2K atomics across 8 lines instead of 16K on one line.
__global__ __launch_bounds__(256) void dispatch_kernel(
    const int* __restrict__ top_e, const float* __restrict__ top_w,
    const int* __restrict__ offs, int* __restrict__ cursor,
    int* __restrict__ tok_list, float* __restrict__ w_list)
{
    int t = blockIdx.x * 256 + threadIdx.x;   // grid 32*256 == 8192 exactly
    int lane = threadIdx.x & 63;
#pragma unroll
    for (int k = 0; k < 2; k++) {
        int e = top_e[t * 2 + k];
        int idx = 0;
#pragma unroll
        for (int ex = 0; ex < EN; ex++) {
            unsigned long long m = __ballot(e == ex);
            if (e == ex) {
                int cnt = __popcll(m);
                int leader = __ffsll(m) - 1;
                int pos = 0;
                if (lane == leader) pos = atomicAdd(&cursor[ex * 16], cnt);
                pos = __shfl(pos, leader, 64);
                int rank = __popcll(m & ((1ull << lane) - 1ull));
                idx = offs[ex] + pos + rank;
            }
        }
        tok_list[idx] = t * 2 + k;            // encode (token, k)
        w_list[idx] = top_w[t * 2 + k];
    }
}

// --------------------------------------- per-expert transpose + bf16 convert
// w1: [E][1024][1024] f32 -> w1b [E][1024][1024] bf16 transposed; same for w2.
__global__ __launch_bounds__(256) void transpose_conv_kernel(
    const float* __restrict__ w1, const float* __restrict__ w2,
    ushort* __restrict__ w1b, ushort* __restrict__ w2b)
{
    __shared__ float tile[32][33];
    int bid = blockIdx.x;
    const float* in; ushort* outp;
    if (bid >= 8192) { in = w2; outp = w2b; bid -= 8192; }
    else             { in = w1; outp = w1b; }
    int e  = bid >> 10;
    int t2 = bid & 1023;
    int tb = t2 >> 5;
    int ta = t2 & 31;
    const float* pin = in + ((size_t)e << 20);
    ushort* pout = outp + ((size_t)e << 20);
    int tx = threadIdx.x & 31, ty = threadIdx.x >> 5;  // ty 0..7
#pragma unroll
    for (int j = 0; j < 4; j++)
        tile[ty + j * 8][tx] = pin[(size_t)(ta * 32 + ty + j * 8) * 1024 + tb * 32 + tx];
    __syncthreads();
#pragma unroll
    for (int j = 0; j < 4; j++)
        pout[(size_t)(tb * 32 + ty + j * 8) * 1024 + ta * 32 + tx] =
            f2bf(tile[tx][ty + j * 8]);
}

// =================== grouped GEMM core (shared by map / reduce) =============
// 128x128 tile, BK=64, 4 waves, global_load_lds(16B), XOR-swizzled LDS.

// --------------------------------------------------------- grouped map GEMM
__global__ __launch_bounds__(256) void map_gemm(
    const ushort* __restrict__ xb, const ushort* __restrict__ w1b,
    ushort* __restrict__ hbuf,
    const int* __restrict__ tok_list, const float* __restrict__ w_list,
    const int* __restrict__ offs)
{
    __shared__ __align__(16) short lA[128 * 64];
    __shared__ __align__(16) short lB[128 * 64];
    __shared__ int   tok_s[128];
    __shared__ float wt_s[128];

    int e = blockIdx.x >> 6;
    int rb = blockIdx.x & 63;
    int base = offs[e], cnt = offs[e + 1] - base;
    int row0 = rb << 7;
    if (row0 >= cnt) return;
    int rem = cnt - row0;
    int tid = threadIdx.x;
    if (tid < 128) {
        int r = row0 + tid; if (r > cnt - 1) r = cnt - 1;   // clamp
        tok_s[tid] = tok_list[base + r];
        wt_s[tid]  = w_list[base + r];
    }
    __syncthreads();

    int lane = tid & 63, wid = tid >> 6;
    int wr = wid >> 1, wc = wid & 1;
    int nb = blockIdx.y;

    // staging source pointers (4 A + 4 B per thread), pre-swizzled k-segment
    int srl  = lane >> 3;                         // row low bits == row&7
    int kseg = ((lane & 7) ^ srl) << 3;           // shorts within row
    const ushort* pA[4]; const ushort* pB[4];
    const ushort* wbase = w1b + ((size_t)e << 20);
#pragma unroll
    for (int i = 0; i < 4; i++) {
        int row = wid * 32 + i * 8 + srl;
        pA[i] = xb + (size_t)(tok_s[row] >> 1) * HD + kseg;
        pB[i] = wbase + (size_t)(nb * 128 + row) * HD + kseg;
    }
    short* ldsA = lA + wid * 2048;   // wave-uniform: wid*4096 bytes
    short* ldsB = lB + wid * 2048;

    f32x4 acc[4][4];
#pragma unroll
    for (int m = 0; m < 4; m++)
#pragma unroll
        for (int n = 0; n < 4; n++) acc[m][n] = (f32x4){0.f, 0.f, 0.f, 0.f};

    for (int k0 = 0; k0 < HD; k0 += 64) {
#pragma unroll
        for (int i = 0; i < 4; i++) {
            gload16(pA[i], ldsA + i * 512);
            gload16(pB[i], ldsB + i * 512);
            pA[i] += 64; pB[i] += 64;
        }
        __syncthreads();
        bf16x8 af[4][2], bg[4][2];
        int rx = lane & 7, hi = lane >> 4, lo = lane & 15;
#pragma unroll
        for (int m = 0; m < 4; m++) {
            int R = wr * 64 + m * 16 + lo;
#pragma unroll
            for (int ks = 0; ks < 2; ks++)
                af[m][ks] = *(const bf16x8*)&lA[R * 64 + (((ks * 4 + hi) ^ rx) << 3)];
        }
#pragma unroll
        for (int n = 0; n < 4; n++) {
            int R = wc * 64 + n * 16 + lo;
#pragma unroll
            for (int ks = 0; ks < 2; ks++)
                bg[n][ks] = *(const bf16x8*)&lB[R * 64 + (((ks * 4 + hi) ^ rx) << 3)];
        }
#pragma unroll
        for (int ks = 0; ks < 2; ks++)
#pragma unroll
            for (int m = 0; m < 4; m++)
#pragma unroll
                for (int n = 0; n < 4; n++)
                    acc[m][n] = __builtin_amdgcn_mfma_f32_16x16x32_bf16(af[m][ks], bg[n][ks], acc[m][n], 0, 0, 0);
        __syncthreads();
    }

    // ---- epilogue: weight-fold, bf16, LDS transpose, 16B coalesced stores
    short* ep = (wid < 2 ? lA : lB) + (wid & 1) * 4096;   // 8KB per wave
    int lo = lane & 15, hi = lane >> 4;
#pragma unroll
    for (int m = 0; m < 4; m++)
#pragma unroll
        for (int r = 0; r < 4; r++) {
            int row_l = m * 16 + hi * 4 + r;
            int rswz = (row_l & 7) << 4;
            float w = wt_s[wr * 64 + row_l];
#pragma unroll
            for (int n = 0; n < 4; n++) {
                int colb = (n * 16 + lo) * 2;
                ep[(row_l * 128 + (colb ^ rswz)) >> 1] = f2bf(acc[m][n][r] * w);
            }
        }
    __syncthreads();
    size_t outbase = (size_t)(base + row0);
    int colg0 = (nb << 7) + wc * 64;
#pragma unroll
    for (int j = 0; j < 8; j++) {
        int row_l = j * 8 + (lane >> 3);
        int r_blk = wr * 64 + row_l;
        int sb = ((lane & 7) * 16) ^ ((row_l & 7) << 4);
        bf16x8 v = *(const bf16x8*)&ep[(row_l * 128 + sb) >> 1];
        if (r_blk < rem)
            *(bf16x8*)&hbuf[(outbase + r_blk) * FD + colg0 + (lane & 7) * 8] = v;
    }
}

// ------------------------------------------------------ grouped reduce GEMM
// obuf[v][:] = h[row][:] @ w2[e]  (v = tok_list row id = t*2+k), bf16 out.
__global__ __launch_bounds__(256) void reduce_gemm(
    const ushort* __restrict__ hbuf, const ushort* __restrict__ w2b,
    ushort* __restrict__ obuf,
    const int* __restrict__ tok_list, const int* __restrict__ offs)
{
    __shared__ __align__(16) short lA[128 * 64];
    __shared__ __align__(16) short lB[128 * 64];
    __shared__ int tok_s[128];

    int e = blockIdx.x >> 6;
    int rb = blockIdx.x & 63;
    int base = offs[e], cnt = offs[e + 1] - base;
    int row0 = rb << 7;
    if (row0 >= cnt) return;
    int rem = cnt - row0;
    int tid = threadIdx.x;
    if (tid < 128) {
        int r = row0 + tid; if (r > cnt - 1) r = cnt - 1;
        tok_s[tid] = tok_list[base + r];
    }
    __syncthreads();

    int lane = tid & 63, wid = tid >> 6;
    int wr = wid >> 1, wc = wid & 1;
    int nb = blockIdx.y;

    int srl  = lane >> 3;
    int kseg = ((lane & 7) ^ srl) << 3;
    const ushort* pA[4]; const ushort* pB[4];
    const ushort* wbase = w2b + ((size_t)e << 20);
#pragma unroll
    for (int i = 0; i < 4; i++) {
        int row = wid * 32 + i * 8 + srl;
        int ar = row0 + row; if (ar > cnt - 1) ar = cnt - 1;
        pA[i] = hbuf + (size_t)(base + ar) * FD + kseg;
        pB[i] = wbase + (size_t)(nb * 128 + row) * FD + kseg;
    }
    short* ldsA = lA + wid * 2048;
    short* ldsB = lB + wid * 2048;

    f32x4 acc[4][4];
#pragma unroll
    for (int m = 0; m < 4; m++)
#pragma unroll
        for (int n = 0; n < 4; n++) acc[m][n] = (f32x4){0.f, 0.f, 0.f, 0.f};

    for (int k0 = 0; k0 < FD; k0 += 64) {
#pragma unroll
        for (int i = 0; i < 4; i++) {
            gload16(pA[i], ldsA + i * 512);
            gload16(pB[i], ldsB + i * 512);
            pA[i] += 64; pB[i] += 64;
        }
        __syncthreads();
        bf16x8 af[4][2], bg[4][2];
        int rx = lane & 7, hi = lane >> 4, lo = lane & 15;
#pragma unroll
        for (int m = 0; m < 4; m++) {
            int R = wr * 64 + m * 16 + lo;
#pragma unroll
            for (int ks = 0; ks < 2; ks++)
                af[m][ks] = *(const bf16x8*)&lA[R * 64 + (((ks * 4 + hi) ^ rx) << 3)];
        }
#pragma unroll
        for (int n = 0; n < 4; n++) {
            int R = wc * 64 + n * 16 + lo;
#pragma unroll
            for (int ks = 0; ks < 2; ks++)
                bg[n][ks] = *(const bf16x8*)&lB[R * 64 + (((ks * 4 + hi) ^ rx) << 3)];
        }
#pragma unroll
        for (int ks = 0; ks < 2; ks++)
#pragma unroll
            for (int m = 0; m < 4; m++)
#pragma unroll
                for (int n = 0; n < 4; n++)
                    acc[m][n] = __builtin_amdgcn_mfma_f32_16x16x32_bf16(af[m][ks], bg[n][ks], acc[m][n], 0, 0, 0);
        __syncthreads();
    }

    // ---- epilogue: bf16, LDS transpose, scatter rows (128B segments)
    short* ep = (wid < 2 ? lA : lB) + (wid & 1) * 4096;
    int lo = lane & 15, hi = lane >> 4;
#pragma unroll
    for (int m = 0; m < 4; m++)
#pragma unroll
        for (int r = 0; r < 4; r++) {
            int row_l = m * 16 + hi * 4 + r;
            int rswz = (row_l & 7) << 4;
#pragma unroll
            for (int n = 0; n < 4; n++) {
                int colb = (n * 16 + lo) * 2;
                ep[(row_l * 128 + (colb ^ rswz)) >> 1] = f2bf(acc[m][n][r]);
            }
        }
    __syncthreads();
    int colg0 = (nb << 7) + wc * 64;
#pragma unroll
    for (int j = 0; j < 8; j++) {
        int row_l = j * 8 + (lane >> 3);
        int r_blk = wr * 64 + row_l;
        int sb = ((lane & 7) * 16) ^ ((row_l & 7) << 4);
        bf16x8 v = *(const bf16x8*)&ep[(row_l * 128 + sb) >> 1];
        if (r_blk < rem)
            *(bf16x8*)&obuf[(size_t)tok_s[r_blk] * HD + colg0 + (lane & 7) * 8] = v;
    }
}

// ------------------------------------------------------------------ combine
// out[t][h] = obuf[2t][h] + obuf[2t+1][h]; fully coalesced.
__global__ __launch_bounds__(256) void combine_kernel(
    const ushort* __restrict__ obuf, float* __restrict__ out)
{
    int g = blockIdx.x * 256 + threadIdx.x;      // grid 4096 -> 1M threads
    int t = g >> 7, c8 = (g & 127) << 3;
    const ushort* p = obuf + (size_t)t * 2048 + c8;
    bf16x8 a = *(const bf16x8*)p;
    bf16x8 b = *(const bf16x8*)(p + 1024);
    float o[8];
#pragma unroll
    for (int i = 0; i < 8; i++)
        o[i] = bf2f((ushort)a[i]) + bf2f((ushort)b[i]);
    float* q = out + (size_t)t * HD + c8;
    *(float4*)q       = (float4){o[0], o[1], o[2], o[3]};
    *(float4*)(q + 4) = (float4){o[4], o[5], o[6], o[7]};
}

// ---------------------------------------------------------------- launcher
extern "C" void kernel_launch(void* const* d_in, const int* in_sizes, int n_in,
                              void* d_out, int out_size, void* d_ws, size_t ws_size,
                              hipStream_t stream)
{
    const float* x   = (const float*)d_in[0];
    const float* wrt = (const float*)d_in[1];
    const float* w1  = (const float*)d_in[2];
    const float* w2  = (const float*)d_in[3];
    float* out = (float*)d_out;

    // workspace carve (~80.3 MB); obuf aliases xb+w1b (dead after map_gemm)
    uint8_t* ws = (uint8_t*)d_ws;
    ushort* xb   = (ushort*)(ws);                    // 16 MB  [T][H] bf16
    ushort* w1b  = (ushort*)(ws + (16u << 20));      // 16 MB  [E][F][H] bf16
    ushort* obuf = (ushort*)(ws);                    // 32 MB  [2T][H] bf16 (alias)
    ushort* w2b  = (ushort*)(ws + (32u << 20));      // 16 MB  [E][H][F] bf16
    ushort* hbuf = (ushort*)(ws + (48u << 20));      // 32 MB  [2T][F] bf16
    uint8_t* p80 = ws + (80u << 20);
    int*   tok_list = (int*)(p80);                   // 64 KB
    float* w_list   = (float*)(p80 + (64u << 10));   // 64 KB
    int*   top_e    = (int*)(p80 + (128u << 10));    // 64 KB
    float* top_w    = (float*)(p80 + (192u << 10));  // 64 KB
    uint8_t* ctr    = p80 + (256u << 10);
    int*   counts   = (int*)(ctr);                   // 8 ints
    float* probsum  = (float*)(ctr + 64);            // 8 floats
    int*   offs     = (int*)(ctr + 128);             // 9 ints
    int*   cursor   = (int*)(ctr + 256);             // 8 * 16 ints (padded lines)
    float* loss_out = out + 8388608;

    hipMemsetAsync(ctr, 0, 1024, stream);

    router_kernel<<<2048, 256, 0, stream>>>(x, wrt, xb, top_e, top_w, counts, probsum);
    prep_kernel<<<1, 1, 0, stream>>>(counts, probsum, offs, loss_out);
    dispatch_kernel<<<32, 256, 0, stream>>>(top_e, top_w, offs, cursor, tok_list, w_list);
    transpose_conv_kernel<<<16384, 256, 0, stream>>>(w1, w2, w1b, w2b);
    map_gemm<<<dim3(512, 8), 256, 0, stream>>>(xb, w1b, hbuf, tok_list, w_list, offs);
    reduce_gemm<<<dim3(512, 8), 256, 0, stream>>>(hbuf, w2b, obuf, tok_list, offs);
    combine_kernel<<<4096, 256, 0, stream>>>(obuf, out);
}

// Round 4
// 225.373 us; speedup vs baseline: 1.6871x; 1.1157x over previous
//
#include <hip/hip_runtime.h>
#include <hip/hip_bf16.h>
#include <stdint.h>

// dMoA forward: router(+x->bf16) -> dispatch (ballot-aggregated) ->
// grouped map GEMM (H->F) -> grouped reduce GEMM (F->H, per-(t,k) rows) ->
// coalesced combine.  T=8192 tokens, H=F=1024, E=8, top-k=2.
// GEMMs: 256x256 tile, BK=64, 8 waves, 2-phase dbuf (stage-ahead + 1 barrier
// per K-step), XOR-swizzled LDS, expert-pinned-to-XCD grid.

#define HD 1024
#define FD 1024
#define EN 8

typedef __attribute__((ext_vector_type(8))) short bf16x8;
typedef __attribute__((ext_vector_type(4))) float f32x4;

__device__ __forceinline__ void gload16(const void* g, void* l) {
    __builtin_amdgcn_global_load_lds(
        (const __attribute__((address_space(1))) unsigned int*)g,
        (__attribute__((address_space(3))) unsigned int*)l, 16, 0, 0);
}

__device__ __forceinline__ ushort f2bf(float v) {
    __hip_bfloat16 h = __float2bfloat16(v);
    return *(ushort*)&h;
}
__device__ __forceinline__ float bf2f(ushort u) {
    unsigned int w = ((unsigned int)u) << 16;
    float f; __builtin_memcpy(&f, &w, 4); return f;
}

// ------------------------------------------------- router (+ x -> bf16 cast)
__global__ __launch_bounds__(256) void router_kernel(
    const float* __restrict__ x, const float* __restrict__ wrt,
    ushort* __restrict__ xb,
    int* __restrict__ top_e, float* __restrict__ top_w,
    int* __restrict__ counts, float* __restrict__ probsum)
{
    __shared__ int   cnt_s[EN];
    __shared__ float ps_s[EN];
    int tid = threadIdx.x;
    if (tid < EN) { cnt_s[tid] = 0; ps_s[tid] = 0.f; }
    __syncthreads();

    int wid = tid >> 6, lane = tid & 63;
    int t = blockIdx.x * 4 + wid;            // grid 2048 * 4 waves = 8192
    const float4* xr4 = (const float4*)(x + (size_t)t * HD);
    ushort4* xbo = (ushort4*)(xb + (size_t)t * HD);
    float acc[EN];
#pragma unroll
    for (int e = 0; e < EN; e++) acc[e] = 0.f;
#pragma unroll
    for (int it = 0; it < 4; it++) {
        float4 xv = xr4[it * 64 + lane];
        ushort4 o; o.x = f2bf(xv.x); o.y = f2bf(xv.y); o.z = f2bf(xv.z); o.w = f2bf(xv.w);
        xbo[it * 64 + lane] = o;
        int h0 = it * 256 + lane * 4;
        float xs[4] = {xv.x, xv.y, xv.z, xv.w};
#pragma unroll
        for (int j = 0; j < 4; j++) {
            const float4* wp = (const float4*)(wrt + (size_t)(h0 + j) * EN);
            float4 wa = wp[0], wb = wp[1];
            acc[0] += xs[j] * wa.x; acc[1] += xs[j] * wa.y;
            acc[2] += xs[j] * wa.z; acc[3] += xs[j] * wa.w;
            acc[4] += xs[j] * wb.x; acc[5] += xs[j] * wb.y;
            acc[6] += xs[j] * wb.z; acc[7] += xs[j] * wb.w;
        }
    }
#pragma unroll
    for (int off = 32; off >= 1; off >>= 1) {
#pragma unroll
        for (int e = 0; e < EN; e++) acc[e] += __shfl_xor(acc[e], off, 64);
    }
    if (lane == 0) {
        float m = acc[0];
#pragma unroll
        for (int e = 1; e < EN; e++) m = fmaxf(m, acc[e]);
        float p[EN], s = 0.f;
#pragma unroll
        for (int e = 0; e < EN; e++) { p[e] = expf(acc[e] - m); s += p[e]; }
        float inv = 1.f / s;
#pragma unroll
        for (int e = 0; e < EN; e++) p[e] *= inv;
        int e0 = 0;
#pragma unroll
        for (int e = 1; e < EN; e++) if (p[e] > p[e0]) e0 = e;   // strict >, first wins
        int e1 = (e0 == 0) ? 1 : 0;
#pragma unroll
        for (int e = 0; e < EN; e++) {
            if (e == e0) continue;
            if (p[e] > p[e1]) e1 = e;
        }
        top_e[t * 2] = e0;  top_e[t * 2 + 1] = e1;
        top_w[t * 2] = p[e0]; top_w[t * 2 + 1] = p[e1];
        atomicAdd(&cnt_s[e0], 1); atomicAdd(&cnt_s[e1], 1);
#pragma unroll
        for (int e = 0; e < EN; e++) atomicAdd(&ps_s[e], p[e]);
    }
    __syncthreads();
    if (tid < EN) {
        atomicAdd(&counts[tid], cnt_s[tid]);
        atomicAdd(&probsum[tid], ps_s[tid]);
    }
}

// ------------------------------------------------------------- prep (1 thread)
__global__ void prep_kernel(const int* __restrict__ counts,
                            const float* __restrict__ probsum,
                            int* __restrict__ offs, float* __restrict__ loss_out)
{
    int off = 0; float loss = 0.f;
    for (int e = 0; e < EN; e++) {
        offs[e] = off;
        off += counts[e];
        loss += ((float)counts[e] / 16384.f) * (probsum[e] / 8192.f);
    }
    offs[EN] = off;
    *loss_out = 8.f * loss;
}

// ---------------------------------------------------------------- dispatch
// Per-wave ballot aggregation: 1 atomic per (wave, expert, k) onto padded
// cachelines.
__global__ __launch_bounds__(256) void dispatch_kernel(
    const int* __restrict__ top_e, const float* __restrict__ top_w,
    const int* __restrict__ offs, int* __restrict__ cursor,
    int* __restrict__ tok_list, float* __restrict__ w_list)
{
    int t = blockIdx.x * 256 + threadIdx.x;   // grid 32*256 == 8192 exactly
    int lane = threadIdx.x & 63;
#pragma unroll
    for (int k = 0; k < 2; k++) {
        int e = top_e[t * 2 + k];
        int idx = 0;
#pragma unroll
        for (int ex = 0; ex < EN; ex++) {
            unsigned long long m = __ballot(e == ex);
            if (e == ex) {
                int cnt = __popcll(m);
                int leader = __ffsll(m) - 1;
                int pos = 0;
                if (lane == leader) pos = atomicAdd(&cursor[ex * 16], cnt);
                pos = __shfl(pos, leader, 64);
                int rank = __popcll(m & ((1ull << lane) - 1ull));
                idx = offs[ex] + pos + rank;
            }
        }
        tok_list[idx] = t * 2 + k;            // encode (token, k)
        w_list[idx] = top_w[t * 2 + k];
    }
}

// --------------------------------------- per-expert transpose + bf16 convert
__global__ __launch_bounds__(256) void transpose_conv_kernel(
    const float* __restrict__ w1, const float* __restrict__ w2,
    ushort* __restrict__ w1b, ushort* __restrict__ w2b)
{
    __shared__ float tile[32][33];
    int bid = blockIdx.x;
    const float* in; ushort* outp;
    if (bid >= 8192) { in = w2; outp = w2b; bid -= 8192; }
    else             { in = w1; outp = w1b; }
    int e  = bid >> 10;
    int t2 = bid & 1023;
    int tb = t2 >> 5;
    int ta = t2 & 31;
    const float* pin = in + ((size_t)e << 20);
    ushort* pout = outp + ((size_t)e << 20);
    int tx = threadIdx.x & 31, ty = threadIdx.x >> 5;  // ty 0..7
#pragma unroll
    for (int j = 0; j < 4; j++)
        tile[ty + j * 8][tx] = pin[(size_t)(ta * 32 + ty + j * 8) * 1024 + tb * 32 + tx];
    __syncthreads();
#pragma unroll
    for (int j = 0; j < 4; j++)
        pout[(size_t)(tb * 32 + ty + j * 8) * 1024 + ta * 32 + tx] =
            f2bf(tile[tx][ty + j * 8]);
}

// =================== grouped GEMM core =====================================
// 256x256 tile, BK=64, 8 waves (2M x 4N), dbuf LDS, stage-ahead 2-phase.
// Grid flat 1024: g&7 = expert (pins expert to one XCD), (g>>3)&3 = nb,
// (g>>5) = rb (32 slots -> covers any count up to 8192).

// --------------------------------------------------------- grouped map GEMM
__global__ __launch_bounds__(512, 2) void map_gemm(
    const ushort* __restrict__ xb, const ushort* __restrict__ w1b,
    ushort* __restrict__ hbuf,
    const int* __restrict__ tok_list, const float* __restrict__ w_list,
    const int* __restrict__ offs)
{
    __shared__ __align__(16) short lA[2][256][64];   // 64 KB
    __shared__ __align__(16) short lB[2][256][64];   // 64 KB
    __shared__ int   tok_s[256];
    __shared__ float wt_s[256];

    int g = blockIdx.x;
    int e = g & 7, q = g >> 3, nb = q & 3, rb = q >> 2;
    int base = offs[e], cnt = offs[e + 1] - base;
    int row0 = rb << 8;
    if (row0 >= cnt) return;
    int rem = cnt - row0;
    int tid = threadIdx.x;
    if (tid < 256) {
        int r = row0 + tid; if (r > cnt - 1) r = cnt - 1;   // clamp
        tok_s[tid] = tok_list[base + r];
        wt_s[tid]  = w_list[base + r];
    }
    __syncthreads();

    int lane = tid & 63, w = tid >> 6;
    int wm = w >> 2, wn = w & 3;
    int w32 = w * 32;
    int lr = lane >> 3;
    int kseg = ((lane & 7) ^ lr) << 3;        // pre-inverse-swizzled k-seg

    const ushort* pA[4]; const ushort* pB[4];
    const ushort* wbase = w1b + ((size_t)e << 20);
#pragma unroll
    for (int i = 0; i < 4; i++) {
        int rowT = w32 + i * 8 + lr;
        pA[i] = xb + (size_t)(tok_s[rowT] >> 1) * HD + kseg;
        pB[i] = wbase + (size_t)(nb * 256 + rowT) * HD + kseg;
    }

    f32x4 acc[8][4];
#pragma unroll
    for (int m = 0; m < 8; m++)
#pragma unroll
        for (int n = 0; n < 4; n++) acc[m][n] = (f32x4){0.f, 0.f, 0.f, 0.f};

    // prologue: stage K-tile 0 into buf0
#pragma unroll
    for (int i = 0; i < 4; i++) {
        gload16(pA[i], &lA[0][w32 + i * 8][0]);
        gload16(pB[i], &lB[0][w32 + i * 8][0]);
        pA[i] += 64; pB[i] += 64;
    }
    __syncthreads();

    int lo = lane & 15, hi = lane >> 4, rx = lane & 7;
    for (int t = 0; t < 16; ++t) {
        int cur = t & 1;
        if (t < 15) {                          // stage next tile first
            int nxt = cur ^ 1;
#pragma unroll
            for (int i = 0; i < 4; i++) {
                gload16(pA[i], &lA[nxt][w32 + i * 8][0]);
                gload16(pB[i], &lB[nxt][w32 + i * 8][0]);
                pA[i] += 64; pB[i] += 64;
            }
        }
#pragma unroll
        for (int ks = 0; ks < 2; ks++) {
            bf16x8 af[8], bg[4];
#pragma unroll
            for (int m = 0; m < 8; m++)
                af[m] = *(const bf16x8*)&lA[cur][wm * 128 + m * 16 + lo][((ks * 4 + hi) ^ rx) << 3];
#pragma unroll
            for (int n = 0; n < 4; n++)
                bg[n] = *(const bf16x8*)&lB[cur][wn * 64 + n * 16 + lo][((ks * 4 + hi) ^ rx) << 3];
#pragma unroll
            for (int m = 0; m < 8; m++)
#pragma unroll
                for (int n = 0; n < 4; n++)
                    acc[m][n] = __builtin_amdgcn_mfma_f32_16x16x32_bf16(af[m], bg[n], acc[m][n], 0, 0, 0);
        }
        __syncthreads();                       // publishes staged tile, guards reuse
    }

    // ---- epilogue: weight-fold, bf16, per-wave LDS transpose, 16B stores
    short* ep = (w < 4 ? (short*)lA : (short*)lB) + (w & 3) * 8192;  // 16KB/wave
#pragma unroll
    for (int m = 0; m < 8; m++)
#pragma unroll
        for (int r = 0; r < 4; r++) {
            int row_l = m * 16 + hi * 4 + r;
            int rswz = (row_l & 7) << 4;
            float wgt = wt_s[wm * 128 + row_l];
#pragma unroll
            for (int n = 0; n < 4; n++) {
                int colb = (n * 16 + lo) * 2;
                ep[(row_l * 128 + (colb ^ rswz)) >> 1] = f2bf(acc[m][n][r] * wgt);
            }
        }
    __syncthreads();
    size_t outbase = (size_t)(base + row0);
    int colg0 = (nb << 8) + wn * 64;
#pragma unroll
    for (int j = 0; j < 16; j++) {
        int row_l = j * 8 + (lane >> 3);
        int r_blk = wm * 128 + row_l;
        int sb = ((lane & 7) * 16) ^ ((row_l & 7) << 4);
        bf16x8 v = *(const bf16x8*)&ep[(row_l * 128 + sb) >> 1];
        if (r_blk < rem)
            *(bf16x8*)&hbuf[(outbase + r_blk) * FD + colg0 + (lane & 7) * 8] = v;
    }
}

// ------------------------------------------------------ grouped reduce GEMM
// obuf[v][:] = h[row][:] @ w2[e]  (v = tok_list row id = t*2+k), bf16 out.
__global__ __launch_bounds__(512, 2) void reduce_gemm(
    const ushort* __restrict__ hbuf, const ushort* __restrict__ w2b,
    ushort* __restrict__ obuf,
    const int* __restrict__ tok_list, const int* __restrict__ offs)
{
    __shared__ __align__(16) short lA[2][256][64];
    __shared__ __align__(16) short lB[2][256][64];
    __shared__ int tok_s[256];

    int g = blockIdx.x;
    int e = g & 7, q = g >> 3, nb = q & 3, rb = q >> 2;
    int base = offs[e], cnt = offs[e + 1] - base;
    int row0 = rb << 8;
    if (row0 >= cnt) return;
    int rem = cnt - row0;
    int tid = threadIdx.x;
    if (tid < 256) {
        int r = row0 + tid; if (r > cnt - 1) r = cnt - 1;
        tok_s[tid] = tok_list[base + r];
    }
    __syncthreads();

    int lane = tid & 63, w = tid >> 6;
    int wm = w >> 2, wn = w & 3;
    int w32 = w * 32;
    int lr = lane >> 3;
    int kseg = ((lane & 7) ^ lr) << 3;

    const ushort* pA[4]; const ushort* pB[4];
    const ushort* wbase = w2b + ((size_t)e << 20);
#pragma unroll
    for (int i = 0; i < 4; i++) {
        int rowT = w32 + i * 8 + lr;
        int ar = row0 + rowT; if (ar > cnt - 1) ar = cnt - 1;
        pA[i] = hbuf + (size_t)(base + ar) * FD + kseg;
        pB[i] = wbase + (size_t)(nb * 256 + rowT) * FD + kseg;
    }

    f32x4 acc[8][4];
#pragma unroll
    for (int m = 0; m < 8; m++)
#pragma unroll
        for (int n = 0; n < 4; n++) acc[m][n] = (f32x4){0.f, 0.f, 0.f, 0.f};

#pragma unroll
    for (int i = 0; i < 4; i++) {
        gload16(pA[i], &lA[0][w32 + i * 8][0]);
        gload16(pB[i], &lB[0][w32 + i * 8][0]);
        pA[i] += 64; pB[i] += 64;
    }
    __syncthreads();

    int lo = lane & 15, hi = lane >> 4, rx = lane & 7;
    for (int t = 0; t < 16; ++t) {
        int cur = t & 1;
        if (t < 15) {
            int nxt = cur ^ 1;
#pragma unroll
            for (int i = 0; i < 4; i++) {
                gload16(pA[i], &lA[nxt][w32 + i * 8][0]);
                gload16(pB[i], &lB[nxt][w32 + i * 8][0]);
                pA[i] += 64; pB[i] += 64;
            }
        }
#pragma unroll
        for (int ks = 0; ks < 2; ks++) {
            bf16x8 af[8], bg[4];
#pragma unroll
            for (int m = 0; m < 8; m++)
                af[m] = *(const bf16x8*)&lA[cur][wm * 128 + m * 16 + lo][((ks * 4 + hi) ^ rx) << 3];
#pragma unroll
            for (int n = 0; n < 4; n++)
                bg[n] = *(const bf16x8*)&lB[cur][wn * 64 + n * 16 + lo][((ks * 4 + hi) ^ rx) << 3];
#pragma unroll
            for (int m = 0; m < 8; m++)
#pragma unroll
                for (int n = 0; n < 4; n++)
                    acc[m][n] = __builtin_amdgcn_mfma_f32_16x16x32_bf16(af[m], bg[n], acc[m][n], 0, 0, 0);
        }
        __syncthreads();
    }

    // ---- epilogue: bf16, per-wave LDS transpose, scatter rows (128B segs)
    short* ep = (w < 4 ? (short*)lA : (short*)lB) + (w & 3) * 8192;
#pragma unroll
    for (int m = 0; m < 8; m++)
#pragma unroll
        for (int r = 0; r < 4; r++) {
            int row_l = m * 16 + hi * 4 + r;
            int rswz = (row_l & 7) << 4;
#pragma unroll
            for (int n = 0; n < 4; n++) {
                int colb = (n * 16 + lo) * 2;
                ep[(row_l * 128 + (colb ^ rswz)) >> 1] = f2bf(acc[m][n][r]);
            }
        }
    __syncthreads();
    int colg0 = (nb << 8) + wn * 64;
#pragma unroll
    for (int j = 0; j < 16; j++) {
        int row_l = j * 8 + (lane >> 3);
        int r_blk = wm * 128 + row_l;
        int sb = ((lane & 7) * 16) ^ ((row_l & 7) << 4);
        bf16x8 v = *(const bf16x8*)&ep[(row_l * 128 + sb) >> 1];
        if (r_blk < rem)
            *(bf16x8*)&obuf[(size_t)tok_s[r_blk] * HD + colg0 + (lane & 7) * 8] = v;
    }
}

// ------------------------------------------------------------------ combine
__global__ __launch_bounds__(256) void combine_kernel(
    const ushort* __restrict__ obuf, float* __restrict__ out)
{
    int g = blockIdx.x * 256 + threadIdx.x;      // grid 4096 -> 1M threads
    int t = g >> 7, c8 = (g & 127) << 3;
    const ushort* p = obuf + (size_t)t * 2048 + c8;
    bf16x8 a = *(const bf16x8*)p;
    bf16x8 b = *(const bf16x8*)(p + 1024);
    float o[8];
#pragma unroll
    for (int i = 0; i < 8; i++)
        o[i] = bf2f((ushort)a[i]) + bf2f((ushort)b[i]);
    float* q = out + (size_t)t * HD + c8;
    *(float4*)q       = (float4){o[0], o[1], o[2], o[3]};
    *(float4*)(q + 4) = (float4){o[4], o[5], o[6], o[7]};
}

// ---------------------------------------------------------------- launcher
extern "C" void kernel_launch(void* const* d_in, const int* in_sizes, int n_in,
                              void* d_out, int out_size, void* d_ws, size_t ws_size,
                              hipStream_t stream)
{
    const float* x   = (const float*)d_in[0];
    const float* wrt = (const float*)d_in[1];
    const float* w1  = (const float*)d_in[2];
    const float* w2  = (const float*)d_in[3];
    float* out = (float*)d_out;

    // workspace carve (~80.3 MB); obuf aliases xb+w1b (dead after map_gemm)
    uint8_t* ws = (uint8_t*)d_ws;
    ushort* xb   = (ushort*)(ws);                    // 16 MB  [T][H] bf16
    ushort* w1b  = (ushort*)(ws + (16u << 20));      // 16 MB  [E][F][H] bf16
    ushort* obuf = (ushort*)(ws);                    // 32 MB  [2T][H] bf16 (alias)
    ushort* w2b  = (ushort*)(ws + (32u << 20));      // 16 MB  [E][H][F] bf16
    ushort* hbuf = (ushort*)(ws + (48u << 20));      // 32 MB  [2T][F] bf16
    uint8_t* p80 = ws + (80u << 20);
    int*   tok_list = (int*)(p80);                   // 64 KB
    float* w_list   = (float*)(p80 + (64u << 10));   // 64 KB
    int*   top_e    = (int*)(p80 + (128u << 10));    // 64 KB
    float* top_w    = (float*)(p80 + (192u << 10));  // 64 KB
    uint8_t* ctr    = p80 + (256u << 10);
    int*   counts   = (int*)(ctr);                   // 8 ints
    float* probsum  = (float*)(ctr + 64);            // 8 floats
    int*   offs     = (int*)(ctr + 128);             // 9 ints
    int*   cursor   = (int*)(ctr + 256);             // 8 * 16 ints (padded lines)
    float* loss_out = out + 8388608;

    hipMemsetAsync(ctr, 0, 1024, stream);

    router_kernel<<<2048, 256, 0, stream>>>(x, wrt, xb, top_e, top_w, counts, probsum);
    prep_kernel<<<1, 1, 0, stream>>>(counts, probsum, offs, loss_out);
    dispatch_kernel<<<32, 256, 0, stream>>>(top_e, top_w, offs, cursor, tok_list, w_list);
    transpose_conv_kernel<<<16384, 256, 0, stream>>>(w1, w2, w1b, w2b);
    map_gemm<<<1024, 512, 0, stream>>>(xb, w1b, hbuf, tok_list, w_list, offs);
    reduce_gemm<<<1024, 512, 0, stream>>>(hbuf, w2b, obuf, tok_list, offs);
    combine_kernel<<<4096, 256, 0, stream>>>(obuf, out);
}